// Round 2
// baseline (102.914 us; speedup 1.0000x reference)
//
#include <hip/hip_runtime.h>

// loss[b] = (beta1 - beta2)^2 - intersection   (see reference)
//   true: (B,4,4) fp32; pred: (B,10,3) fp32, rows 0..3 used.
//
// R2: fully-coalesced global loads via block-level LDS staging.
//   - block = 256 threads = 256 records
//   - true : 1024 float4 loaded contiguously, scattered to LDS stride-17
//   - pred : 3840 float2 loaded contiguously, only floats 0..11 of each
//            record kept, scattered to LDS stride-13
//   odd LDS strides -> wave64 b32 reads are 2 lanes/bank (conflict-free).

#define RPB 256  // records per block

__global__ __launch_bounds__(256) void boxloss_kernel(
    const float* __restrict__ T, const float* __restrict__ P,
    float* __restrict__ out, int B)
{
    __shared__ float sT[RPB * 17];  // 17408 B
    __shared__ float sP[RPB * 13];  // 13312 B

    const int t = threadIdx.x;
    const int blockBase = blockIdx.x * RPB;

    // ---- stage true: contiguous float4 loads ----
    {
        const float4* Tg = reinterpret_cast<const float4*>(T) + (size_t)blockBase * 4;
        const long long totalF4 = (long long)B * 4;
        #pragma unroll
        for (int k = 0; k < 4; ++k) {
            int g = t + k * RPB;                 // float4 index within block (0..1023)
            if ((long long)blockBase * 4 + g < totalF4) {
                float4 v = Tg[g];
                int r = g >> 2, q = g & 3;
                int a = r * 17 + q * 4;
                sT[a] = v.x; sT[a + 1] = v.y; sT[a + 2] = v.z; sT[a + 3] = v.w;
            }
        }
    }

    // ---- stage pred: contiguous float2 loads, keep floats 0..11 ----
    {
        const float2* Pg = reinterpret_cast<const float2*>(P + (size_t)blockBase * 30);
        const long long totalF2 = (long long)B * 15;
        #pragma unroll
        for (int k = 0; k < 15; ++k) {
            int g = t + k * RPB;                 // float2 index within block (0..3839)
            if ((long long)blockBase * 15 + g < totalF2) {
                float2 v = Pg[g];
                int r = g / 15, h = g % 15;      // record, float2-within-record
                if (h < 6) {                     // floats 2h,2h+1 in [0,12)
                    int a = r * 13 + h * 2;
                    sP[a] = v.x; sP[a + 1] = v.y;
                }
            }
        }
    }

    __syncthreads();

    const int b = blockBase + t;
    if (b >= B) return;

    // ---- gather my record from LDS (2-way banked, free) ----
    float tmnx[4], tmny[4], tmxx[4], tmxy[4];
    {
        const float* tp = &sT[t * 17];
        #pragma unroll
        for (int i = 0; i < 4; ++i) {
            tmnx[i] = tp[4 * i];     tmny[i] = tp[4 * i + 1];
            tmxx[i] = tp[4 * i + 2]; tmxy[i] = tp[4 * i + 3];
        }
    }
    float pmnx[4], pmny[4], pmxx[4], pmxy[4];
    {
        const float* pp = &sP[t * 13];
        #pragma unroll
        for (int j = 0; j < 4; ++j) {
            float p0 = pp[3 * j], p1 = pp[3 * j + 1], p2 = pp[3 * j + 2];
            float mn = fminf(p0, p2), mx = fmaxf(p0, p2);
            pmnx[j] = mn; pmxx[j] = mx; pmny[j] = p1; pmxy[j] = p1 + (mx - mn);
        }
    }

    // ---- 4x4 reductions ----
    float inter = 0.f, b1 = 0.f, b2 = 0.f;
    #pragma unroll
    for (int i = 0; i < 4; ++i) {
        #pragma unroll
        for (int j = 0; j < 4; ++j) {
            float xo = fmaxf(0.f, fminf(tmxx[i], pmxx[j]) - fmaxf(tmnx[i], pmnx[j]));
            float yo = fmaxf(0.f, fminf(tmxy[i], pmxy[j]) - fmaxf(tmny[i], pmny[j]));
            inter += xo * yo;
            float x1 = fmaxf(0.f, fminf(tmxx[i], tmxx[j]) - fmaxf(tmnx[i], tmnx[j]));
            float y1 = fmaxf(0.f, fminf(tmxy[i], tmxy[j]) - fmaxf(tmny[i], tmny[j]));
            float a1 = x1 * y1;
            float x2 = fmaxf(0.f, fminf(pmxx[i], pmxx[j]) - fmaxf(pmnx[i], pmnx[j]));
            float y2 = fmaxf(0.f, fminf(pmxy[i], pmxy[j]) - fmaxf(pmny[i], pmny[j]));
            float a2 = x2 * y2;
            b1 += (i == j) ? a1 * a1 : a1;
            b2 += (i == j) ? a2 * a2 : a2;
        }
    }
    float d = b1 - b2;
    out[b] = d * d - inter;
}

extern "C" void kernel_launch(void* const* d_in, const int* in_sizes, int n_in,
                              void* d_out, int out_size, void* d_ws, size_t ws_size,
                              hipStream_t stream)
{
    const float* T = (const float*)d_in[0];   // true: B*16 floats
    const float* P = (const float*)d_in[1];   // pred: B*30 floats
    float* out = (float*)d_out;               // B floats
    int B = in_sizes[0] / 16;

    int grid = (B + RPB - 1) / RPB;
    boxloss_kernel<<<grid, 256, 0, stream>>>(T, P, out, B);
}

// Round 3
// 79.852 us; speedup vs baseline: 1.2888x; 1.2888x over previous
//
#include <hip/hip_runtime.h>

// loss[b] = (beta1 - beta2)^2 - intersection   (see reference)
//   true: (B,4,4) fp32; pred: (B,10,3) fp32, rows 0..3 used.
//
// R3: two records per thread (record pair = 240B of pred, 16B-aligned)
//   - true : 8x float4 per thread, all bytes used
//   - pred : 7x float4 per thread (indices 0,1,2,7,8,9,10 of the 15-f4 pair)
//   - out  : 1x float2 store per thread
//   - beta via symmetry: diag cheap (pred needs no clamp; true does),
//     off-diag upper triangle x2.

__device__ __forceinline__ float record_loss(
    const float tmnx[4], const float tmny[4], const float tmxx[4], const float tmxy[4],
    const float pf[12])
{
    float pmnx[4], pmny[4], pmxx[4], pmxy[4];
    #pragma unroll
    for (int j = 0; j < 4; ++j) {
        float p0 = pf[3 * j], p1 = pf[3 * j + 1], p2 = pf[3 * j + 2];
        float mn = fminf(p0, p2), mx = fmaxf(p0, p2);
        pmnx[j] = mn; pmxx[j] = mx; pmny[j] = p1; pmxy[j] = p1 + (mx - mn);
    }

    float inter = 0.f;
    #pragma unroll
    for (int i = 0; i < 4; ++i) {
        #pragma unroll
        for (int j = 0; j < 4; ++j) {
            float xo = fmaxf(0.f, fminf(tmxx[i], pmxx[j]) - fmaxf(tmnx[i], pmnx[j]));
            float yo = fmaxf(0.f, fminf(tmxy[i], pmxy[j]) - fmaxf(tmny[i], pmny[j]));
            inter += xo * yo;
        }
    }

    float b1 = 0.f, b2 = 0.f;
    // diagonal: self-overlap of box i with itself = max(0, w) * max(0, h).
    // pred boxes are ordered by construction (w,h >= 0); true is raw random.
    #pragma unroll
    for (int i = 0; i < 4; ++i) {
        float w1 = fmaxf(0.f, tmxx[i] - tmnx[i]);
        float h1 = fmaxf(0.f, tmxy[i] - tmny[i]);
        float a1 = w1 * h1;
        float w2 = pmxx[i] - pmnx[i];
        float h2 = pmxy[i] - pmny[i];
        float a2 = w2 * h2;
        b1 += a1 * a1;
        b2 += a2 * a2;
    }
    // off-diagonal pairs, counted twice
    #pragma unroll
    for (int i = 0; i < 4; ++i) {
        #pragma unroll
        for (int j = i + 1; j < 4; ++j) {
            float x1 = fmaxf(0.f, fminf(tmxx[i], tmxx[j]) - fmaxf(tmnx[i], tmnx[j]));
            float y1 = fmaxf(0.f, fminf(tmxy[i], tmxy[j]) - fmaxf(tmny[i], tmny[j]));
            b1 += 2.f * (x1 * y1);
            float x2 = fmaxf(0.f, fminf(pmxx[i], pmxx[j]) - fmaxf(pmnx[i], pmnx[j]));
            float y2 = fmaxf(0.f, fminf(pmxy[i], pmxy[j]) - fmaxf(pmny[i], pmny[j]));
            b2 += 2.f * (x2 * y2);
        }
    }
    float d = b1 - b2;
    return d * d - inter;
}

__global__ __launch_bounds__(256) void boxloss_kernel(
    const float* __restrict__ T, const float* __restrict__ P,
    float* __restrict__ out, int B)
{
    const int t = blockIdx.x * blockDim.x + threadIdx.x;
    const int nPairs = (B + 1) >> 1;
    if (t >= nPairs) return;
    const bool hasB = (2 * t + 1) < B;

    // ---- true: 8x float4 (two records, 128B, fully used) ----
    const float4* T4 = reinterpret_cast<const float4*>(T) + (size_t)t * 8;
    float4 tv[8];
    #pragma unroll
    for (int k = 0; k < 4; ++k) tv[k] = T4[k];
    if (hasB) {
        #pragma unroll
        for (int k = 4; k < 8; ++k) tv[k] = T4[k];
    }

    // ---- pred: 7x float4 out of the 15 covering the 240B pair ----
    const float4* P4 = reinterpret_cast<const float4*>(P) + (size_t)t * 15;
    float4 v0 = P4[0], v1 = P4[1], v2 = P4[2];
    float4 v7, v8, v9, v10;
    if (hasB) { v7 = P4[7]; v8 = P4[8]; v9 = P4[9]; v10 = P4[10]; }

    // ---- record A (index 2t) ----
    float lossA, lossB = 0.f;
    {
        float tmnx[4], tmny[4], tmxx[4], tmxy[4];
        #pragma unroll
        for (int i = 0; i < 4; ++i) {
            tmnx[i] = (&tv[0])[i].x; tmny[i] = (&tv[0])[i].y;
            tmxx[i] = (&tv[0])[i].z; tmxy[i] = (&tv[0])[i].w;
        }
        float pf[12] = { v0.x, v0.y, v0.z, v0.w, v1.x, v1.y, v1.z, v1.w,
                         v2.x, v2.y, v2.z, v2.w };
        lossA = record_loss(tmnx, tmny, tmxx, tmxy, pf);
    }

    // ---- record B (index 2t+1): pred floats 30..41 of the pair ----
    if (hasB) {
        float tmnx[4], tmny[4], tmxx[4], tmxy[4];
        #pragma unroll
        for (int i = 0; i < 4; ++i) {
            tmnx[i] = (&tv[4])[i].x; tmny[i] = (&tv[4])[i].y;
            tmxx[i] = (&tv[4])[i].z; tmxy[i] = (&tv[4])[i].w;
        }
        float pf[12] = { v7.z, v7.w, v8.x, v8.y, v8.z, v8.w,
                         v9.x, v9.y, v9.z, v9.w, v10.x, v10.y };
        lossB = record_loss(tmnx, tmny, tmxx, tmxy, pf);
    }

    if (hasB) {
        float2 r; r.x = lossA; r.y = lossB;
        reinterpret_cast<float2*>(out)[t] = r;
    } else {
        out[2 * t] = lossA;
    }
}

extern "C" void kernel_launch(void* const* d_in, const int* in_sizes, int n_in,
                              void* d_out, int out_size, void* d_ws, size_t ws_size,
                              hipStream_t stream)
{
    const float* T = (const float*)d_in[0];   // true: B*16 floats
    const float* P = (const float*)d_in[1];   // pred: B*30 floats
    float* out = (float*)d_out;               // B floats
    int B = in_sizes[0] / 16;

    int nPairs = (B + 1) / 2;
    int block = 256;
    int grid = (nPairs + block - 1) / block;
    boxloss_kernel<<<grid, block, 0, stream>>>(T, P, out, B);
}

// Round 4
// 71.731 us; speedup vs baseline: 1.4347x; 1.1132x over previous
//
#include <hip/hip_runtime.h>

// loss[b] = (beta1 - beta2)^2 - intersection   (see reference)
//   true: (B,4,4) fp32; pred: (B,10,3) fp32, rows 0..3 used.
//
// R4: fully-coalesced float4 global loads via per-wave LDS staging.
//   - wave (64 lanes) owns 64 records
//   - true : 256 f4/wave, contiguous loads -> XOR-swizzled LDS (p = s ^ ((s>>3)&7))
//            both write (s=64k+l) and read (s=4l+k) are bank-uniform
//   - pred : 480 f4/wave, contiguous loads -> linear LDS; per-record reads as
//            6x float2 at word 30l (8B-aligned; ~4-way on 3 merged instrs, negligible)
//   - no div/mod, no scatter predication; single __syncthreads()
//   - B = 2^21 -> grid divides exactly; clamps kept for safety, dormant.

__device__ __forceinline__ float record_loss(
    const float tmnx[4], const float tmny[4], const float tmxx[4], const float tmxy[4],
    const float pf[12])
{
    float pmnx[4], pmny[4], pmxx[4], pmxy[4];
    #pragma unroll
    for (int j = 0; j < 4; ++j) {
        float p0 = pf[3 * j], p1 = pf[3 * j + 1], p2 = pf[3 * j + 2];
        float mn = fminf(p0, p2), mx = fmaxf(p0, p2);
        pmnx[j] = mn; pmxx[j] = mx; pmny[j] = p1; pmxy[j] = p1 + (mx - mn);
    }

    float inter = 0.f;
    #pragma unroll
    for (int i = 0; i < 4; ++i) {
        #pragma unroll
        for (int j = 0; j < 4; ++j) {
            float xo = fmaxf(0.f, fminf(tmxx[i], pmxx[j]) - fmaxf(tmnx[i], pmnx[j]));
            float yo = fmaxf(0.f, fminf(tmxy[i], pmxy[j]) - fmaxf(tmny[i], pmny[j]));
            inter += xo * yo;
        }
    }

    float b1 = 0.f, b2 = 0.f;
    #pragma unroll
    for (int i = 0; i < 4; ++i) {
        float w1 = fmaxf(0.f, tmxx[i] - tmnx[i]);
        float h1 = fmaxf(0.f, tmxy[i] - tmny[i]);
        float a1 = w1 * h1;
        float w2 = pmxx[i] - pmnx[i];
        float h2 = pmxy[i] - pmny[i];
        float a2 = w2 * h2;
        b1 += a1 * a1;
        b2 += a2 * a2;
    }
    #pragma unroll
    for (int i = 0; i < 4; ++i) {
        #pragma unroll
        for (int j = i + 1; j < 4; ++j) {
            float x1 = fmaxf(0.f, fminf(tmxx[i], tmxx[j]) - fmaxf(tmnx[i], tmnx[j]));
            float y1 = fmaxf(0.f, fminf(tmxy[i], tmxy[j]) - fmaxf(tmny[i], tmny[j]));
            b1 += 2.f * (x1 * y1);
            float x2 = fmaxf(0.f, fminf(pmxx[i], pmxx[j]) - fmaxf(pmnx[i], pmnx[j]));
            float y2 = fmaxf(0.f, fminf(pmxy[i], pmxy[j]) - fmaxf(pmny[i], pmny[j]));
            b2 += 2.f * (x2 * y2);
        }
    }
    float d = b1 - b2;
    return d * d - inter;
}

__global__ __launch_bounds__(256) void boxloss_kernel(
    const float* __restrict__ T, const float* __restrict__ P,
    float* __restrict__ out, int B)
{
    __shared__ float4 sT[4][256];   // 16 KiB : true, xor-swizzled per wave
    __shared__ float  sP[4][1920];  // 30 KiB : pred, linear per wave

    const int t = threadIdx.x;
    const int w = t >> 6;   // wave in block
    const int l = t & 63;   // lane
    const long long waveBase = (long long)blockIdx.x * 256 + (w << 6);

    // ---- stage true: 4 contiguous float4 per lane ----
    {
        const float4* T4 = reinterpret_cast<const float4*>(T);
        const long long base = waveBase << 2;
        const long long maxI = ((long long)B << 2) - 1;
        #pragma unroll
        for (int k = 0; k < 4; ++k) {
            int s = (k << 6) + l;                 // 0..255
            long long gi = base + s; if (gi > maxI) gi = maxI;
            int p = s ^ ((s >> 3) & 7);
            sT[w][p] = T4[gi];
        }
    }
    // ---- stage pred: 480 contiguous float4 per wave ----
    {
        const float4* P4 = reinterpret_cast<const float4*>(P);
        const long long base = (waveBase >> 1) * 15;
        const long long maxI = ((long long)B >> 1) * 15 - 1;
        float4* sPw = reinterpret_cast<float4*>(sP[w]);
        #pragma unroll
        for (int k = 0; k < 8; ++k) {
            int s = (k << 6) + l;                 // 0..511
            if (s < 480) {
                long long gi = base + s; if (gi > maxI) gi = maxI;
                sPw[s] = P4[gi];
            }
        }
    }

    __syncthreads();

    // ---- gather my record ----
    float tmnx[4], tmny[4], tmxx[4], tmxy[4];
    #pragma unroll
    for (int k = 0; k < 4; ++k) {
        int s = (l << 2) + k;
        int p = s ^ ((s >> 3) & 7);
        float4 v = sT[w][p];
        tmnx[k] = v.x; tmny[k] = v.y; tmxx[k] = v.z; tmxy[k] = v.w;
    }
    float pf[12];
    {
        const float2* pp = reinterpret_cast<const float2*>(sP[w] + 30 * l);
        #pragma unroll
        for (int j = 0; j < 6; ++j) {
            float2 v = pp[j];
            pf[2 * j] = v.x; pf[2 * j + 1] = v.y;
        }
    }

    float loss = record_loss(tmnx, tmny, tmxx, tmxy, pf);

    long long b = waveBase + l;
    if (b < B) out[b] = loss;
}

extern "C" void kernel_launch(void* const* d_in, const int* in_sizes, int n_in,
                              void* d_out, int out_size, void* d_ws, size_t ws_size,
                              hipStream_t stream)
{
    const float* T = (const float*)d_in[0];   // true: B*16 floats
    const float* P = (const float*)d_in[1];   // pred: B*30 floats
    float* out = (float*)d_out;               // B floats
    int B = in_sizes[0] / 16;

    int grid = (B + 255) / 256;
    boxloss_kernel<<<grid, 256, 0, stream>>>(T, P, out, B);
}